// Round 1
// baseline (2815.248 us; speedup 1.0000x reference)
//
#include <hip/hip_runtime.h>
#include <hip/hip_bf16.h>
#include <math.h>

// MHA forward, fp32 baseline.
//   B=4, T=2048, D=1024, H=16, hd=64.
// Pipeline: 3x GEMM (QKV, scatter to [B,H,T,hd]) -> causal flash attention
//           -> GEMM (+bias) to d_out.
// Workspace: Q,K,V,attnOut = 4 x 32MiB = 128MiB of d_ws.

#define B_SZ 4
#define T_SEQ 2048
#define D_MODEL 1024
#define NH 16
#define HD 64

// ---------------------------------------------------------------------------
// GEMM: C = A @ W^T (+ bias), A[M,K] row-major, W[N,K] row-major.
// OUT_MODE 0: C row-major [M,N], add bias.
// OUT_MODE 1: scatter C to [B, H, T, hd]  (m = b*T+t, n = h*64+d), no bias.
// 128x128 tile, 256 threads, 8x8 micro-tile, BK=8.
// ---------------------------------------------------------------------------
template<int OUT_MODE>
__global__ __launch_bounds__(256)
void gemm_xwt(const float* __restrict__ A, const float* __restrict__ W,
              const float* __restrict__ bias, float* __restrict__ C,
              int M, int N, int K)
{
    __shared__ __align__(16) float As[8][132];   // [k][m], pad 132 -> no write conflicts
    __shared__ __align__(16) float Bs[8][132];   // [k][n]
    const int t   = threadIdx.x;
    const int m0  = blockIdx.y * 128;
    const int n0  = blockIdx.x * 128;
    const int srow = t >> 1;       // 0..127 staging row
    const int skq  = t & 1;        // which float4 of the 8 k's

    const float* Ap = A + (size_t)(m0 + srow) * K + skq * 4;
    const float* Bp = W + (size_t)(n0 + srow) * K + skq * 4;

    const int tm = t & 15;         // micro-tile row group
    const int tn = t >> 4;         // micro-tile col group

    float acc[8][8];
#pragma unroll
    for (int i = 0; i < 8; ++i)
#pragma unroll
        for (int j = 0; j < 8; ++j) acc[i][j] = 0.f;

    for (int k0 = 0; k0 < K; k0 += 8) {
        const float4 av = *(const float4*)(Ap + k0);
        const float4 bv = *(const float4*)(Bp + k0);
        __syncthreads();
        As[skq*4+0][srow] = av.x;
        As[skq*4+1][srow] = av.y;
        As[skq*4+2][srow] = av.z;
        As[skq*4+3][srow] = av.w;
        Bs[skq*4+0][srow] = bv.x;
        Bs[skq*4+1][srow] = bv.y;
        Bs[skq*4+2][srow] = bv.z;
        Bs[skq*4+3][srow] = bv.w;
        __syncthreads();
#pragma unroll
        for (int k = 0; k < 8; ++k) {
            const float4 a0 = *(const float4*)&As[k][tm*8];
            const float4 a1 = *(const float4*)&As[k][tm*8+4];
            const float4 b0 = *(const float4*)&Bs[k][tn*8];
            const float4 b1 = *(const float4*)&Bs[k][tn*8+4];
            const float a[8] = {a0.x,a0.y,a0.z,a0.w,a1.x,a1.y,a1.z,a1.w};
            const float b[8] = {b0.x,b0.y,b0.z,b0.w,b1.x,b1.y,b1.z,b1.w};
#pragma unroll
            for (int i = 0; i < 8; ++i)
#pragma unroll
                for (int j = 0; j < 8; ++j)
                    acc[i][j] = fmaf(a[i], b[j], acc[i][j]);
        }
    }

    if (OUT_MODE == 0) {
#pragma unroll
        for (int i = 0; i < 8; ++i) {
            const int m = m0 + tm*8 + i;
#pragma unroll
            for (int jq = 0; jq < 2; ++jq) {
                const int n = n0 + tn*8 + jq*4;
                float4 o;
                o.x = acc[i][jq*4+0] + bias[n+0];
                o.y = acc[i][jq*4+1] + bias[n+1];
                o.z = acc[i][jq*4+2] + bias[n+2];
                o.w = acc[i][jq*4+3] + bias[n+3];
                *(float4*)&C[(size_t)m * N + n] = o;
            }
        }
    } else {
#pragma unroll
        for (int i = 0; i < 8; ++i) {
            const int m  = m0 + tm*8 + i;
            const int bb = m >> 11;            // m / T_SEQ
            const int tr = m & (T_SEQ - 1);
#pragma unroll
            for (int jq = 0; jq < 2; ++jq) {
                const int n  = n0 + tn*8 + jq*4;
                const int hh = n >> 6;
                const int dd = n & 63;
                float4 o;
                o.x = acc[i][jq*4+0]; o.y = acc[i][jq*4+1];
                o.z = acc[i][jq*4+2]; o.w = acc[i][jq*4+3];
                *(float4*)&C[(((size_t)bb*NH + hh)*T_SEQ + tr)*HD + dd] = o;
            }
        }
    }
}

// ---------------------------------------------------------------------------
// Causal flash attention, fp32, online softmax.
// Q,K,V: [B,H,T,hd]; O: [B,T,H*hd].
// Block = 256 threads = 4 waves; each wave owns 4 consecutive query rows
// (16 rows/block), so each 64-key K/V tile is amortized over 16 rows.
// Score phase: lane owns key j (K rows XOR-swizzled for conflict-free b128).
// PV phase:    lane owns dim d  (V column reads stride-68, conflict-free b32;
//              p broadcast from per-wave LDS).
// ---------------------------------------------------------------------------
__global__ __launch_bounds__(256)
void attn_fwd(const float* __restrict__ Q, const float* __restrict__ Kg,
              const float* __restrict__ Vg, float* __restrict__ O)
{
    __shared__ __align__(16) float Ks[64*64];     // swizzled row-major
    __shared__ __align__(16) float Vs[64*68];     // row-major, stride 68
    __shared__ __align__(16) float q_lds[4][4][64];
    __shared__ __align__(16) float p_lds[4][4][64];

    const int t    = threadIdx.x;
    const int lane = t & 63;
    const int w    = t >> 6;
    const int rb   = blockIdx.x;          // 0..T/16-1
    const int bh   = blockIdx.y;          // 0..B*H-1
    const int b    = bh >> 4;
    const int h    = bh & 15;

    const int row0 = rb*16 + w*4;         // this wave's first query row
    const float* qbase = Q + ((size_t)bh * T_SEQ + row0) * HD;
#pragma unroll
    for (int r = 0; r < 4; ++r)
        q_lds[w][r][lane] = qbase[r*HD + lane] * 0.125f;   // fold 1/sqrt(64)

    float acc[4]   = {0.f, 0.f, 0.f, 0.f};      // lane owns output dim d=lane
    float m_run[4] = {-1e30f, -1e30f, -1e30f, -1e30f};
    float l_run[4] = {0.f, 0.f, 0.f, 0.f};

    const int maxrow = rb*16 + 15;
    const int ntiles = maxrow/64 + 1;
    const float* kgb = Kg + (size_t)bh * T_SEQ * HD;
    const float* vgb = Vg + (size_t)bh * T_SEQ * HD;

    for (int tt = 0; tt < ntiles; ++tt) {
        __syncthreads();   // previous tile's compute done before overwrite
        // ---- stage K (swizzled) and V (stride 68) ----
#pragma unroll
        for (int i = 0; i < 4; ++i) {
            const int f  = i*256 + t;       // float4 index 0..1023
            const int j  = f >> 4;          // key row in tile
            const int c4 = f & 15;          // float4 column
            const float4 kk = *(const float4*)(kgb + ((size_t)(tt*64 + j))*HD + c4*4);
            *(float4*)&Ks[j*64 + ((c4 ^ (j & 15)) << 2)] = kk;
            const float4 vv = *(const float4*)(vgb + ((size_t)(tt*64 + j))*HD + c4*4);
            *(float4*)&Vs[j*68 + c4*4] = vv;
        }
        __syncthreads();

        // ---- scores: lane owns key j = lane ----
        float s[4] = {0.f, 0.f, 0.f, 0.f};
        const float* krow = &Ks[lane*64];
        const int lx = lane & 15;
#pragma unroll
        for (int dq = 0; dq < 16; ++dq) {
            const float4 kk = *(const float4*)&krow[(dq ^ lx) << 2];
#pragma unroll
            for (int r = 0; r < 4; ++r) {
                const float4 qq = *(const float4*)&q_lds[w][r][dq*4];  // broadcast
                s[r] = fmaf(kk.x, qq.x, s[r]);
                s[r] = fmaf(kk.y, qq.y, s[r]);
                s[r] = fmaf(kk.z, qq.z, s[r]);
                s[r] = fmaf(kk.w, qq.w, s[r]);
            }
        }

        // ---- online softmax per row ----
        const int key = tt*64 + lane;
#pragma unroll
        for (int r = 0; r < 4; ++r) {
            if (key > row0 + r) s[r] = -1e30f;
            float mt = s[r];
#pragma unroll
            for (int o = 32; o; o >>= 1) mt = fmaxf(mt, __shfl_xor(mt, o));
            const float mn  = fmaxf(m_run[r], mt);
            const float p   = __expf(s[r] - mn);
            float su = p;
#pragma unroll
            for (int o = 32; o; o >>= 1) su += __shfl_xor(su, o);
            const float fac = __expf(m_run[r] - mn);
            l_run[r] = l_run[r] * fac + su;
            acc[r]  *= fac;
            m_run[r] = mn;
            p_lds[w][r][lane] = p;
        }
        __builtin_amdgcn_wave_barrier();   // keep p writes before p reads

        // ---- PV: lane owns dim d = lane ----
#pragma unroll
        for (int jq = 0; jq < 16; ++jq) {
            const float4 p0 = *(const float4*)&p_lds[w][0][jq*4];  // broadcast
            const float4 p1 = *(const float4*)&p_lds[w][1][jq*4];
            const float4 p2 = *(const float4*)&p_lds[w][2][jq*4];
            const float4 p3 = *(const float4*)&p_lds[w][3][jq*4];
            const float* pp0 = (const float*)&p0;
            const float* pp1 = (const float*)&p1;
            const float* pp2 = (const float*)&p2;
            const float* pp3 = (const float*)&p3;
#pragma unroll
            for (int e = 0; e < 4; ++e) {
                const float vv = Vs[(jq*4 + e)*68 + lane];
                acc[0] = fmaf(pp0[e], vv, acc[0]);
                acc[1] = fmaf(pp1[e], vv, acc[1]);
                acc[2] = fmaf(pp2[e], vv, acc[2]);
                acc[3] = fmaf(pp3[e], vv, acc[3]);
            }
        }
    }

    // ---- write O[b, row, h*64 + d] ----
    float* ob = O + ((size_t)b * T_SEQ + row0) * D_MODEL + h * HD;
#pragma unroll
    for (int r = 0; r < 4; ++r)
        ob[r*D_MODEL + lane] = acc[r] / l_run[r];
}

// ---------------------------------------------------------------------------
extern "C" void kernel_launch(void* const* d_in, const int* in_sizes, int n_in,
                              void* d_out, int out_size, void* d_ws, size_t ws_size,
                              hipStream_t stream)
{
    const float* x  = (const float*)d_in[0];
    const float* Wq = (const float*)d_in[1];
    const float* Wk = (const float*)d_in[2];
    const float* Wv = (const float*)d_in[3];
    const float* Wo = (const float*)d_in[4];
    const float* bo = (const float*)d_in[5];
    float* out = (float*)d_out;

    float* ws = (float*)d_ws;
    const size_t SZ = (size_t)B_SZ * NH * T_SEQ * HD;   // 8,388,608 floats
    float* Qb = ws;
    float* Kb = ws + SZ;
    float* Vb = ws + 2*SZ;
    float* Oa = ws + 3*SZ;   // attention output, [B,T,D]

    const int M = B_SZ * T_SEQ;   // 8192
    const int N = D_MODEL;        // 1024
    const int K = D_MODEL;        // 1024

    dim3 blk(256);
    dim3 gp(N/128, M/128);        // (8, 64)

    gemm_xwt<1><<<gp, blk, 0, stream>>>(x, Wq, nullptr, Qb, M, N, K);
    gemm_xwt<1><<<gp, blk, 0, stream>>>(x, Wk, nullptr, Kb, M, N, K);
    gemm_xwt<1><<<gp, blk, 0, stream>>>(x, Wv, nullptr, Vb, M, N, K);

    dim3 gatt(T_SEQ/16, B_SZ*NH); // (128, 64)
    attn_fwd<<<gatt, blk, 0, stream>>>(Qb, Kb, Vb, Oa);

    gemm_xwt<0><<<gp, blk, 0, stream>>>(Oa, Wo, bo, out, M, N, K);
}

// Round 3
// 1288.511 us; speedup vs baseline: 2.1849x; 2.1849x over previous
//
#include <hip/hip_runtime.h>
#include <hip/hip_bf16.h>
#include <math.h>

// MHA forward. B=4, T=2048, D=1024, H=16, hd=64.
// QKV GEMMs: fp32 vector (K,V epilogues emit split-bf16 hi/lo buffers).
// Attention: MFMA 16x16x32 bf16, split-precision (hi+lo) for Q,K,P,V ->
//            ~fp32 accuracy at matrix-core rate. Swapped QK^T so softmax
//            reduction is lane-local + 2 shfl_xor.
// Final GEMM: fp32 vector + bias.
// Workspace: Q fp32 32MB | Oa fp32 32MB | Khi/Klo/Vhi/Vlo bf16 16MB each = 128MB.

#define B_SZ 4
#define T_SEQ 2048
#define D_MODEL 1024
#define NH 16
#define HD 64

typedef __attribute__((ext_vector_type(8))) short short8;
typedef __attribute__((ext_vector_type(4))) float f32x4;

__device__ __forceinline__ ushort f2bf(float x) {
    union { float f; unsigned u; } c; c.f = x;
    unsigned r = c.u + 0x7fffu + ((c.u >> 16) & 1u);
    return (ushort)(r >> 16);
}
__device__ __forceinline__ float bf2f(ushort h) {
    union { unsigned u; float f; } c; c.u = ((unsigned)h) << 16;
    return c.f;
}
__device__ __forceinline__ unsigned pk2(ushort a, ushort b) {
    return (unsigned)a | ((unsigned)b << 16);
}

// ---------------------------------------------------------------------------
// GEMM: C = A @ W^T (+ bias). A[M,K] rm, W[N,K] rm. 128x128 tile, 256 thr.
// OUT_MODE 0: fp32 row-major [M,N] + bias.
// OUT_MODE 1: fp32 scatter to [B,H,T,hd].
// OUT_MODE 2: split bf16 scatter: hi->Cb0, lo->Cb1, each [B,H,T,hd].
// ---------------------------------------------------------------------------
template<int OUT_MODE>
__global__ __launch_bounds__(256)
void gemm_xwt(const float* __restrict__ A, const float* __restrict__ W,
              const float* __restrict__ bias, float* __restrict__ C,
              ushort* __restrict__ Cb0, ushort* __restrict__ Cb1,
              int M, int N, int K)
{
    __shared__ __align__(16) float As[8][132];
    __shared__ __align__(16) float Bs[8][132];
    const int t    = threadIdx.x;
    const int m0   = blockIdx.y * 128;
    const int n0   = blockIdx.x * 128;
    const int srow = t >> 1;
    const int skq  = t & 1;

    const float* Ap = A + (size_t)(m0 + srow) * K + skq * 4;
    const float* Bp = W + (size_t)(n0 + srow) * K + skq * 4;

    const int tm = t & 15;
    const int tn = t >> 4;

    float acc[8][8];
#pragma unroll
    for (int i = 0; i < 8; ++i)
#pragma unroll
        for (int j = 0; j < 8; ++j) acc[i][j] = 0.f;

    for (int k0 = 0; k0 < K; k0 += 8) {
        const float4 av = *(const float4*)(Ap + k0);
        const float4 bv = *(const float4*)(Bp + k0);
        __syncthreads();
        As[skq*4+0][srow] = av.x;  As[skq*4+1][srow] = av.y;
        As[skq*4+2][srow] = av.z;  As[skq*4+3][srow] = av.w;
        Bs[skq*4+0][srow] = bv.x;  Bs[skq*4+1][srow] = bv.y;
        Bs[skq*4+2][srow] = bv.z;  Bs[skq*4+3][srow] = bv.w;
        __syncthreads();
#pragma unroll
        for (int k = 0; k < 8; ++k) {
            const float4 a0 = *(const float4*)&As[k][tm*8];
            const float4 a1 = *(const float4*)&As[k][tm*8+4];
            const float4 b0 = *(const float4*)&Bs[k][tn*8];
            const float4 b1 = *(const float4*)&Bs[k][tn*8+4];
            const float a[8] = {a0.x,a0.y,a0.z,a0.w,a1.x,a1.y,a1.z,a1.w};
            const float b[8] = {b0.x,b0.y,b0.z,b0.w,b1.x,b1.y,b1.z,b1.w};
#pragma unroll
            for (int i = 0; i < 8; ++i)
#pragma unroll
                for (int j = 0; j < 8; ++j)
                    acc[i][j] = fmaf(a[i], b[j], acc[i][j]);
        }
    }

    if (OUT_MODE == 0) {
#pragma unroll
        for (int i = 0; i < 8; ++i) {
            const int m = m0 + tm*8 + i;
#pragma unroll
            for (int jq = 0; jq < 2; ++jq) {
                const int n = n0 + tn*8 + jq*4;
                float4 o;
                o.x = acc[i][jq*4+0] + bias[n+0];
                o.y = acc[i][jq*4+1] + bias[n+1];
                o.z = acc[i][jq*4+2] + bias[n+2];
                o.w = acc[i][jq*4+3] + bias[n+3];
                *(float4*)&C[(size_t)m * N + n] = o;
            }
        }
    } else if (OUT_MODE == 1) {
#pragma unroll
        for (int i = 0; i < 8; ++i) {
            const int m  = m0 + tm*8 + i;
            const int bb = m >> 11;
            const int tr = m & (T_SEQ - 1);
#pragma unroll
            for (int jq = 0; jq < 2; ++jq) {
                const int n  = n0 + tn*8 + jq*4;
                const int hh = n >> 6;
                const int dd = n & 63;
                float4 o;
                o.x = acc[i][jq*4+0]; o.y = acc[i][jq*4+1];
                o.z = acc[i][jq*4+2]; o.w = acc[i][jq*4+3];
                *(float4*)&C[(((size_t)bb*NH + hh)*T_SEQ + tr)*HD + dd] = o;
            }
        }
    } else {  // OUT_MODE 2: split bf16 scatter
#pragma unroll
        for (int i = 0; i < 8; ++i) {
            const int m  = m0 + tm*8 + i;
            const int bb = m >> 11;
            const int tr = m & (T_SEQ - 1);
#pragma unroll
            for (int jq = 0; jq < 2; ++jq) {
                const int n  = n0 + tn*8 + jq*4;
                const int hh = n >> 6;
                const int dd = n & 63;
                const size_t base = (((size_t)bb*NH + hh)*T_SEQ + tr)*HD + dd;
                ushort h[4], l[4];
#pragma unroll
                for (int e = 0; e < 4; ++e) {
                    const float x = acc[i][jq*4+e];
                    h[e] = f2bf(x);
                    l[e] = f2bf(x - bf2f(h[e]));
                }
                uint2 ph; ph.x = pk2(h[0],h[1]); ph.y = pk2(h[2],h[3]);
                uint2 pl; pl.x = pk2(l[0],l[1]); pl.y = pk2(l[2],l[3]);
                *(uint2*)&Cb0[base] = ph;
                *(uint2*)&Cb1[base] = pl;
            }
        }
    }
}

// ---------------------------------------------------------------------------
// MFMA causal flash attention, split-precision bf16.
// Grid: (T/64, B*H). Block: 256 thr = 4 waves; wave w owns q rows
// [rb*64 + w*16, +16). KV tile = 64 keys, staged hi/lo in LDS.
// Swapped QK^T: s-tile = mfma(A=K, B=Q) -> lane holds 16 scores (j) for
// one q-row (q = lane&15). PV: O = mfma(A=P, B=V), 3 split terms each.
// ---------------------------------------------------------------------------
__global__ __launch_bounds__(256, 2)
void attn_mfma(const float* __restrict__ Qg,
               const ushort* __restrict__ Khi, const ushort* __restrict__ Klo,
               const ushort* __restrict__ Vhi, const ushort* __restrict__ Vlo,
               float* __restrict__ O)
{
    // strides of 72 ushort (144 B = 9*16) keep b128 reads aligned & ~conflict-free
    __shared__ __align__(16) ushort K_lds[2][64][72];   // [hi/lo][key][dim]
    __shared__ __align__(16) ushort V_lds[2][64][72];   // [hi/lo][dim][key]  (transposed)
    __shared__ __align__(16) ushort p_bf [4][2][16][72];// [wave][hi/lo][q][j]

    const int t    = threadIdx.x;
    const int lane = t & 63;
    const int w    = t >> 6;
    const int rb   = blockIdx.x;          // q-block 0..31
    const int bh   = blockIdx.y;          // 0..63
    const int ql   = lane & 15;           // q-col for S/P, key-row for A, d-col for O/V
    const int g    = lane >> 4;           // 16-lane group 0..3

    const int qr0 = rb*64 + w*16;

    // ---- Q fragments to registers (hi/lo split), 1/sqrt(hd) folded ----
    short8 q_h[2], q_l[2];
    {
        const float* qp = Qg + ((size_t)bh * T_SEQ + qr0 + ql) * HD + g*8;
#pragma unroll
        for (int ks = 0; ks < 2; ++ks) {
            float v[8];
            *(float4*)&v[0] = *(const float4*)(qp + ks*32);
            *(float4*)&v[4] = *(const float4*)(qp + ks*32 + 4);
#pragma unroll
            for (int e = 0; e < 8; ++e) {
                const float x = v[e] * 0.125f;
                const ushort h = f2bf(x);
                q_h[ks][e] = (short)h;
                q_l[ks][e] = (short)f2bf(x - bf2f(h));
            }
        }
    }

    f32x4 acc[4];
#pragma unroll
    for (int dt = 0; dt < 4; ++dt) acc[dt] = (f32x4){0.f,0.f,0.f,0.f};
    float m_run = -1e30f, l_run = 0.f;

    const ushort* khb = Khi + (size_t)bh * T_SEQ * HD;
    const ushort* klb = Klo + (size_t)bh * T_SEQ * HD;
    const ushort* vhb = Vhi + (size_t)bh * T_SEQ * HD;
    const ushort* vlb = Vlo + (size_t)bh * T_SEQ * HD;

    for (int tt = 0; tt <= rb; ++tt) {
        __syncthreads();
        // ---- stage K hi/lo: row-major copy, b128 in/out ----
#pragma unroll
        for (int i = 0; i < 2; ++i) {
            const int idx = i*256 + t;          // 0..511
            const int j   = idx >> 3;
            const int c8  = (idx & 7) * 8;
            const size_t go = ((size_t)(tt*64 + j))*HD + c8;
            *(short8*)&K_lds[0][j][c8] = *(const short8*)(khb + go);
            *(short8*)&K_lds[1][j][c8] = *(const short8*)(klb + go);
        }
        // ---- stage V hi/lo transposed: thread owns (j-pair, 8 dims) ----
        {
            const int jp = t & 31;              // key pair 0..31
            const int c8 = t >> 5;              // dim octet 0..7
            const size_t g0 = ((size_t)(tt*64 + 2*jp))*HD + c8*8;
            const short8 vh0 = *(const short8*)(vhb + g0);
            const short8 vh1 = *(const short8*)(vhb + g0 + HD);
            const short8 vl0 = *(const short8*)(vlb + g0);
            const short8 vl1 = *(const short8*)(vlb + g0 + HD);
#pragma unroll
            for (int dd = 0; dd < 8; ++dd) {
                *(unsigned*)&V_lds[0][c8*8+dd][2*jp] = pk2((ushort)vh0[dd], (ushort)vh1[dd]);
                *(unsigned*)&V_lds[1][c8*8+dd][2*jp] = pk2((ushort)vl0[dd], (ushort)vl1[dd]);
            }
        }
        __syncthreads();

        // ---- QK^T swapped: s[kt] = K-subtile x Q^T (3 split terms) ----
        f32x4 s[4];
#pragma unroll
        for (int kt = 0; kt < 4; ++kt) {
            f32x4 a = (f32x4){0.f,0.f,0.f,0.f};
#pragma unroll
            for (int ks = 0; ks < 2; ++ks) {
                const short8 kh = *(const short8*)&K_lds[0][kt*16 + ql][ks*32 + g*8];
                const short8 kl = *(const short8*)&K_lds[1][kt*16 + ql][ks*32 + g*8];
                a = __builtin_amdgcn_mfma_f32_16x16x32_bf16(kh, q_h[ks], a, 0, 0, 0);
                a = __builtin_amdgcn_mfma_f32_16x16x32_bf16(kh, q_l[ks], a, 0, 0, 0);
                a = __builtin_amdgcn_mfma_f32_16x16x32_bf16(kl, q_h[ks], a, 0, 0, 0);
            }
            s[kt] = a;
        }

        // ---- causal mask (diagonal super-tile only) ----
        if (tt == rb) {
            const int qg = qr0 + ql;
#pragma unroll
            for (int kt = 0; kt < 4; ++kt)
#pragma unroll
                for (int r = 0; r < 4; ++r) {
                    const int jg = tt*64 + kt*16 + g*4 + r;
                    if (jg > qg) s[kt][r] = -1e30f;
                }
        }

        // ---- online softmax: lane-local 16 + xor16 + xor32 ----
        float tmax = s[0][0];
#pragma unroll
        for (int kt = 0; kt < 4; ++kt)
#pragma unroll
            for (int r = 0; r < 4; ++r) tmax = fmaxf(tmax, s[kt][r]);
        tmax = fmaxf(tmax, __shfl_xor(tmax, 16));
        tmax = fmaxf(tmax, __shfl_xor(tmax, 32));
        const float mnew = fmaxf(m_run, tmax);

        float tsum = 0.f;
#pragma unroll
        for (int kt = 0; kt < 4; ++kt)
#pragma unroll
            for (int r = 0; r < 4; ++r) {
                const float p = __expf(s[kt][r] - mnew);
                s[kt][r] = p;
                tsum += p;
            }
        tsum += __shfl_xor(tsum, 16);
        tsum += __shfl_xor(tsum, 32);

        const float fac = __expf(m_run - mnew);
        l_run = l_run * fac + tsum;
        m_run = mnew;

        // rescale O accumulator: O-lane's q = g*4+r lives on lane (g*4+r)
        float facr[4];
#pragma unroll
        for (int r = 0; r < 4; ++r) facr[r] = __shfl(fac, g*4 + r);
#pragma unroll
        for (int dt = 0; dt < 4; ++dt)
#pragma unroll
            for (int r = 0; r < 4; ++r) acc[dt][r] *= facr[r];

        // ---- P -> split bf16, write to per-wave LDS (b64, j-contig) ----
#pragma unroll
        for (int kt = 0; kt < 4; ++kt) {
            ushort h[4], l[4];
#pragma unroll
            for (int r = 0; r < 4; ++r) {
                const float p = s[kt][r];
                h[r] = f2bf(p);
                l[r] = f2bf(p - bf2f(h[r]));
            }
            uint2 ph; ph.x = pk2(h[0],h[1]); ph.y = pk2(h[2],h[3]);
            uint2 pl; pl.x = pk2(l[0],l[1]); pl.y = pk2(l[2],l[3]);
            *(uint2*)&p_bf[w][0][ql][kt*16 + g*4] = ph;
            *(uint2*)&p_bf[w][1][ql][kt*16 + g*4] = pl;
        }
        __asm__ volatile("s_waitcnt lgkmcnt(0)" ::: "memory");
        __builtin_amdgcn_sched_barrier(0);

        // ---- PV: O += P x V (3 split terms) ----
#pragma unroll
        for (int sj = 0; sj < 2; ++sj) {
            const short8 ph = *(const short8*)&p_bf[w][0][ql][sj*32 + g*8];
            const short8 pl = *(const short8*)&p_bf[w][1][ql][sj*32 + g*8];
#pragma unroll
            for (int dt = 0; dt < 4; ++dt) {
                const short8 vh = *(const short8*)&V_lds[0][dt*16 + ql][sj*32 + g*8];
                const short8 vl = *(const short8*)&V_lds[1][dt*16 + ql][sj*32 + g*8];
                acc[dt] = __builtin_amdgcn_mfma_f32_16x16x32_bf16(ph, vh, acc[dt], 0, 0, 0);
                acc[dt] = __builtin_amdgcn_mfma_f32_16x16x32_bf16(ph, vl, acc[dt], 0, 0, 0);
                acc[dt] = __builtin_amdgcn_mfma_f32_16x16x32_bf16(pl, vh, acc[dt], 0, 0, 0);
            }
        }
    }

    // ---- epilogue: normalize, write O[b, q, h*64+d] ----
    float invl[4];
#pragma unroll
    for (int r = 0; r < 4; ++r) invl[r] = 1.0f / __shfl(l_run, g*4 + r);
    float* ob = O + ((size_t)(bh >> 4) * T_SEQ + qr0) * D_MODEL + (bh & 15) * HD;
#pragma unroll
    for (int dt = 0; dt < 4; ++dt)
#pragma unroll
        for (int r = 0; r < 4; ++r)
            ob[(size_t)(g*4 + r) * D_MODEL + dt*16 + ql] = acc[dt][r] * invl[r];
}

// ---------------------------------------------------------------------------
extern "C" void kernel_launch(void* const* d_in, const int* in_sizes, int n_in,
                              void* d_out, int out_size, void* d_ws, size_t ws_size,
                              hipStream_t stream)
{
    const float* x  = (const float*)d_in[0];
    const float* Wq = (const float*)d_in[1];
    const float* Wk = (const float*)d_in[2];
    const float* Wv = (const float*)d_in[3];
    const float* Wo = (const float*)d_in[4];
    const float* bo = (const float*)d_in[5];
    float* out = (float*)d_out;

    const size_t SZ = (size_t)B_SZ * NH * T_SEQ * HD;   // 8,388,608
    float*  ws  = (float*)d_ws;
    float*  Qb  = ws;                   // fp32 [B,H,T,hd]
    float*  Oa  = ws + SZ;              // fp32 [B,T,D]
    ushort* Khi = (ushort*)(ws + 2*SZ);
    ushort* Klo = Khi + SZ;
    ushort* Vhi = Klo + SZ;
    ushort* Vlo = Vhi + SZ;

    const int M = B_SZ * T_SEQ;   // 8192
    const int N = D_MODEL;        // 1024
    const int K = D_MODEL;        // 1024

    dim3 blk(256);
    dim3 gp(N/128, M/128);        // (8, 64)

    gemm_xwt<1><<<gp, blk, 0, stream>>>(x, Wq, nullptr, Qb, nullptr, nullptr, M, N, K);
    gemm_xwt<2><<<gp, blk, 0, stream>>>(x, Wk, nullptr, nullptr, Khi, Klo, M, N, K);
    gemm_xwt<2><<<gp, blk, 0, stream>>>(x, Wv, nullptr, nullptr, Vhi, Vlo, M, N, K);

    dim3 gatt(T_SEQ/64, B_SZ*NH); // (32, 64)
    attn_mfma<<<gatt, blk, 0, stream>>>(Qb, Khi, Klo, Vhi, Vlo, Oa);

    gemm_xwt<0><<<gp, blk, 0, stream>>>(Oa, Wo, bo, out, nullptr, nullptr, M, N, K);
}

// Round 6
// 684.906 us; speedup vs baseline: 4.1104x; 1.8813x over previous
//
#include <hip/hip_runtime.h>
#include <hip/hip_bf16.h>
#include <math.h>

// MHA forward. B=4, T=2048, D=1024, H=16, hd=64.
// All four GEMMs: split-precision bf16 MFMA (3 terms: AhBh+AhBl+AlBh ~ fp32).
//   A (fp32) reg-staged with on-the-fly hi/lo split; W pre-split to bf16 hi/lo.
//   128x128 tile, BK=32, double-buffered LDS, 1 barrier/K-step, XOR swizzle.
// Attention: MFMA split-bf16 flash attention (unchanged from round 3).
// Workspace (128 MB exactly):
//   Qb fp32 32MB | Oa fp32 32MB | Khi/Klo/Vhi/Vlo bf16 16MB each.
//   W splits (4MB) live in dead regions: Wq/Wk/Wv in Oa (pre-attn), Wo in Qb.

#define B_SZ 4
#define T_SEQ 2048
#define D_MODEL 1024
#define NH 16
#define HD 64

typedef __attribute__((ext_vector_type(8))) short short8;
typedef __attribute__((ext_vector_type(4))) float f32x4;

__device__ __forceinline__ ushort f2bf(float x) {
    union { float f; unsigned u; } c; c.f = x;
    unsigned r = c.u + 0x7fffu + ((c.u >> 16) & 1u);
    return (ushort)(r >> 16);
}
__device__ __forceinline__ float bf2f(ushort h) {
    union { unsigned u; float f; } c; c.u = ((unsigned)h) << 16;
    return c.f;
}
__device__ __forceinline__ unsigned pk2(ushort a, ushort b) {
    return (unsigned)a | ((unsigned)b << 16);
}
__device__ __forceinline__ void split8(const float* v, short8& h8, short8& l8) {
#pragma unroll
    for (int e = 0; e < 8; ++e) {
        const ushort h = f2bf(v[e]);
        h8[e] = (short)h;
        l8[e] = (short)f2bf(v[e] - bf2f(h));
    }
}
__device__ __forceinline__ void gload_lds16(ushort* dst, const ushort* src) {
    __builtin_amdgcn_global_load_lds(
        (const __attribute__((address_space(1))) unsigned int*)src,
        (__attribute__((address_space(3))) unsigned int*)dst, 16, 0, 0);
}

// ---------------------------------------------------------------------------
// W split: fp32 [N,K] -> bf16 hi/lo [N,K]. 1M elems, 4/thread.
// ---------------------------------------------------------------------------
__global__ __launch_bounds__(256)
void wsplit(const float* __restrict__ W, ushort* __restrict__ hi,
            ushort* __restrict__ lo)
{
    const int i = (blockIdx.x * 256 + threadIdx.x) * 4;
    const float4 v = *(const float4*)&W[i];
    const float vv[4] = {v.x, v.y, v.z, v.w};
    ushort h[4], l[4];
#pragma unroll
    for (int e = 0; e < 4; ++e) {
        h[e] = f2bf(vv[e]);
        l[e] = f2bf(vv[e] - bf2f(h[e]));
    }
    uint2 ph; ph.x = pk2(h[0],h[1]); ph.y = pk2(h[2],h[3]);
    uint2 pl; pl.x = pk2(l[0],l[1]); pl.y = pk2(l[2],l[3]);
    *(uint2*)&hi[i] = ph;
    *(uint2*)&lo[i] = pl;
}

// ---------------------------------------------------------------------------
// Split-bf16 MFMA GEMM: C = A @ W^T (+bias). A[M,K=1024] fp32 rm,
// Whi/Wlo[N,K] bf16 rm. 128x128 tile, BK=32, 256 thr = 2x2 waves,
// each wave 64x64 = 4x4 16x16 frags, 3 MFMA terms.
// LDS: double buffer x {Ahi,Alo,Bhi,Blo}[128][32] bf16 = 64 KB.
// Swizzle: 16B chunk' = chunk ^ ((row>>1)&3)  (both staged & read sides).
// OUT_MODE 0: fp32 rm + bias. 1: fp32 scatter [B,H,T,hd]. 2: split-bf16 scatter.
// ---------------------------------------------------------------------------
template<int OUT_MODE>
__global__ __launch_bounds__(256, 2)
void gemm_mfma(const float* __restrict__ A,
               const ushort* __restrict__ Bhi, const ushort* __restrict__ Blo,
               const float* __restrict__ bias, float* __restrict__ C,
               ushort* __restrict__ Cb0, ushort* __restrict__ Cb1)
{
    __shared__ __align__(16) ushort smem[2][4][128*32];   // [buf][Ah,Al,Bh,Bl]

    const int t  = threadIdx.x;
    const int w  = t >> 6;
    const int ql = t & 15;
    const int g  = (t & 63) >> 4;
    const int wm = w >> 1;          // wave m index (0..1)
    const int wn = w & 1;           // wave n index (0..1)
    const int n0 = blockIdx.x * 128;
    const int m0 = blockIdx.y * 128;
    const int K  = D_MODEL;

    // A staging geometry: thread owns row arow, k-half kh (16 floats)
    const int arow = t >> 1;
    const int kh   = t & 1;
    const int sA   = (arow >> 1) & 3;
    const float* abase = A + (size_t)(m0 + arow) * K + kh * 16;

    f32x4 acc[4][4];
#pragma unroll
    for (int i = 0; i < 4; ++i)
#pragma unroll
        for (int j = 0; j < 4; ++j) acc[i][j] = (f32x4){0.f,0.f,0.f,0.f};

    const int swz = (ql >> 1) & 3;  // fragment-read swizzle (rows = +ql)

    // ---- staging helpers (lambdas keep regs local) ----
    auto stageB = [&](int bb, int kt) {
#pragma unroll
        for (int i = 0; i < 2; ++i) {
            const int lin = i*256 + t;
            const int row = lin >> 2;
            const int cc  = lin & 3;
            const int scc = cc ^ ((row >> 1) & 3);
            const size_t go = (size_t)(n0 + row) * K + kt*32 + scc*8;
            ushort* dh = &smem[bb][2][(size_t)(i*256 + w*64) * 8];
            ushort* dl = &smem[bb][3][(size_t)(i*256 + w*64) * 8];
            gload_lds16(dh, Bhi + go);
            gload_lds16(dl, Blo + go);
        }
    };
    auto stageA_load = [&](int kt, float4* av) {
        const float* ap = abase + kt*32;
#pragma unroll
        for (int i = 0; i < 4; ++i) av[i] = *(const float4*)(ap + i*4);
    };
    auto stageA_finish = [&](int bb, const float4* av) {
        float vv[16];
#pragma unroll
        for (int i = 0; i < 4; ++i) *(float4*)&vv[i*4] = av[i];
#pragma unroll
        for (int j = 0; j < 2; ++j) {
            short8 h8, l8;
            split8(&vv[j*8], h8, l8);
            const int scc = (kh*2 + j) ^ sA;
            *(short8*)&smem[bb][0][arow*32 + scc*8] = h8;
            *(short8*)&smem[bb][1][arow*32 + scc*8] = l8;
        }
    };
    auto compute = [&](int bb) {
        short8 af[4][2];
#pragma unroll
        for (int mf = 0; mf < 4; ++mf) {
            const int row = wm*64 + mf*16 + ql;
            const int sc  = (g ^ swz) * 8;
            af[mf][0] = *(const short8*)&smem[bb][0][row*32 + sc];
            af[mf][1] = *(const short8*)&smem[bb][1][row*32 + sc];
        }
#pragma unroll
        for (int nf = 0; nf < 4; ++nf) {
            const int rn = wn*64 + nf*16 + ql;
            const int sc = (g ^ swz) * 8;
            const short8 bh8 = *(const short8*)&smem[bb][2][rn*32 + sc];
            const short8 bl8 = *(const short8*)&smem[bb][3][rn*32 + sc];
#pragma unroll
            for (int mf = 0; mf < 4; ++mf) {
                acc[mf][nf] = __builtin_amdgcn_mfma_f32_16x16x32_bf16(af[mf][0], bh8, acc[mf][nf], 0, 0, 0);
                acc[mf][nf] = __builtin_amdgcn_mfma_f32_16x16x32_bf16(af[mf][0], bl8, acc[mf][nf], 0, 0, 0);
                acc[mf][nf] = __builtin_amdgcn_mfma_f32_16x16x32_bf16(af[mf][1], bh8, acc[mf][nf], 0, 0, 0);
            }
        }
    };

    // ---- prologue: stage tile 0 into buf 0 ----
    {
        float4 av[4];
        stageA_load(0, av);
        stageB(0, 0);
        stageA_finish(0, av);
    }

    int cur = 0;
    const int NT = K / 32;          // 32
    for (int kt = 0; kt < NT; ++kt) {
        __syncthreads();            // buf cur staged (all waves drained)
        const bool more = (kt + 1) < NT;
        float4 av[4];
        if (more) {
            stageA_load(kt + 1, av);   // issue early: latency hides under MFMA
            stageB(cur ^ 1, kt + 1);   // async -> other buffer
        }
        compute(cur);
        if (more) stageA_finish(cur ^ 1, av);  // convert + ds_write late
        cur ^= 1;
    }

    // ---- epilogue ----
#pragma unroll
    for (int mf = 0; mf < 4; ++mf) {
#pragma unroll
        for (int nf = 0; nf < 4; ++nf) {
            const int n = n0 + wn*64 + nf*16 + ql;
#pragma unroll
            for (int r = 0; r < 4; ++r) {
                const int m = m0 + wm*64 + mf*16 + g*4 + r;
                const float val = acc[mf][nf][r];
                if (OUT_MODE == 0) {
                    C[(size_t)m * D_MODEL + n] = val + bias[n];
                } else if (OUT_MODE == 1) {
                    const int bb = m >> 11, tr = m & (T_SEQ-1);
                    const int hh = n >> 6,  dd = n & 63;
                    C[(((size_t)bb*NH + hh)*T_SEQ + tr)*HD + dd] = val;
                } else {
                    const int bb = m >> 11, tr = m & (T_SEQ-1);
                    const int hh = n >> 6,  dd = n & 63;
                    const size_t o = (((size_t)bb*NH + hh)*T_SEQ + tr)*HD + dd;
                    const ushort h = f2bf(val);
                    Cb0[o] = h;
                    Cb1[o] = f2bf(val - bf2f(h));
                }
            }
        }
    }
}

// ---------------------------------------------------------------------------
// MFMA causal flash attention, split-precision bf16 (unchanged, round 3).
// ---------------------------------------------------------------------------
__global__ __launch_bounds__(256, 2)
void attn_mfma(const float* __restrict__ Qg,
               const ushort* __restrict__ Khi, const ushort* __restrict__ Klo,
               const ushort* __restrict__ Vhi, const ushort* __restrict__ Vlo,
               float* __restrict__ O)
{
    __shared__ __align__(16) ushort K_lds[2][64][72];
    __shared__ __align__(16) ushort V_lds[2][64][72];
    __shared__ __align__(16) ushort p_bf [4][2][16][72];

    const int t    = threadIdx.x;
    const int lane = t & 63;
    const int w    = t >> 6;
    const int rb   = blockIdx.x;
    const int bh   = blockIdx.y;
    const int ql   = lane & 15;
    const int g    = lane >> 4;

    const int qr0 = rb*64 + w*16;

    short8 q_h[2], q_l[2];
    {
        const float* qp = Qg + ((size_t)bh * T_SEQ + qr0 + ql) * HD + g*8;
#pragma unroll
        for (int ks = 0; ks < 2; ++ks) {
            float v[8];
            *(float4*)&v[0] = *(const float4*)(qp + ks*32);
            *(float4*)&v[4] = *(const float4*)(qp + ks*32 + 4);
#pragma unroll
            for (int e = 0; e < 8; ++e) {
                const float x = v[e] * 0.125f;
                const ushort h = f2bf(x);
                q_h[ks][e] = (short)h;
                q_l[ks][e] = (short)f2bf(x - bf2f(h));
            }
        }
    }

    f32x4 acc[4];
#pragma unroll
    for (int dt = 0; dt < 4; ++dt) acc[dt] = (f32x4){0.f,0.f,0.f,0.f};
    float m_run = -1e30f, l_run = 0.f;

    const ushort* khb = Khi + (size_t)bh * T_SEQ * HD;
    const ushort* klb = Klo + (size_t)bh * T_SEQ * HD;
    const ushort* vhb = Vhi + (size_t)bh * T_SEQ * HD;
    const ushort* vlb = Vlo + (size_t)bh * T_SEQ * HD;

    for (int tt = 0; tt <= rb; ++tt) {
        __syncthreads();
#pragma unroll
        for (int i = 0; i < 2; ++i) {
            const int idx = i*256 + t;
            const int j   = idx >> 3;
            const int c8  = (idx & 7) * 8;
            const size_t go = ((size_t)(tt*64 + j))*HD + c8;
            *(short8*)&K_lds[0][j][c8] = *(const short8*)(khb + go);
            *(short8*)&K_lds[1][j][c8] = *(const short8*)(klb + go);
        }
        {
            const int jp = t & 31;
            const int c8 = t >> 5;
            const size_t g0 = ((size_t)(tt*64 + 2*jp))*HD + c8*8;
            const short8 vh0 = *(const short8*)(vhb + g0);
            const short8 vh1 = *(const short8*)(vhb + g0 + HD);
            const short8 vl0 = *(const short8*)(vlb + g0);
            const short8 vl1 = *(const short8*)(vlb + g0 + HD);
#pragma unroll
            for (int dd = 0; dd < 8; ++dd) {
                *(unsigned*)&V_lds[0][c8*8+dd][2*jp] = pk2((ushort)vh0[dd], (ushort)vh1[dd]);
                *(unsigned*)&V_lds[1][c8*8+dd][2*jp] = pk2((ushort)vl0[dd], (ushort)vl1[dd]);
            }
        }
        __syncthreads();

        f32x4 s[4];
#pragma unroll
        for (int kt = 0; kt < 4; ++kt) {
            f32x4 a = (f32x4){0.f,0.f,0.f,0.f};
#pragma unroll
            for (int ks = 0; ks < 2; ++ks) {
                const short8 kh = *(const short8*)&K_lds[0][kt*16 + ql][ks*32 + g*8];
                const short8 kl = *(const short8*)&K_lds[1][kt*16 + ql][ks*32 + g*8];
                a = __builtin_amdgcn_mfma_f32_16x16x32_bf16(kh, q_h[ks], a, 0, 0, 0);
                a = __builtin_amdgcn_mfma_f32_16x16x32_bf16(kh, q_l[ks], a, 0, 0, 0);
                a = __builtin_amdgcn_mfma_f32_16x16x32_bf16(kl, q_h[ks], a, 0, 0, 0);
            }
            s[kt] = a;
        }

        if (tt == rb) {
            const int qg = qr0 + ql;
#pragma unroll
            for (int kt = 0; kt < 4; ++kt)
#pragma unroll
                for (int r = 0; r < 4; ++r) {
                    const int jg = tt*64 + kt*16 + g*4 + r;
                    if (jg > qg) s[kt][r] = -1e30f;
                }
        }

        float tmax = s[0][0];
#pragma unroll
        for (int kt = 0; kt < 4; ++kt)
#pragma unroll
            for (int r = 0; r < 4; ++r) tmax = fmaxf(tmax, s[kt][r]);
        tmax = fmaxf(tmax, __shfl_xor(tmax, 16));
        tmax = fmaxf(tmax, __shfl_xor(tmax, 32));
        const float mnew = fmaxf(m_run, tmax);

        float tsum = 0.f;
#pragma unroll
        for (int kt = 0; kt < 4; ++kt)
#pragma unroll
            for (int r = 0; r < 4; ++r) {
                const float p = __expf(s[kt][r] - mnew);
                s[kt][r] = p;
                tsum += p;
            }
        tsum += __shfl_xor(tsum, 16);
        tsum += __shfl_xor(tsum, 32);

        const float fac = __expf(m_run - mnew);
        l_run = l_run * fac + tsum;
        m_run = mnew;

        float facr[4];
#pragma unroll
        for (int r = 0; r < 4; ++r) facr[r] = __shfl(fac, g*4 + r);
#pragma unroll
        for (int dt = 0; dt < 4; ++dt)
#pragma unroll
            for (int r = 0; r < 4; ++r) acc[dt][r] *= facr[r];

#pragma unroll
        for (int kt = 0; kt < 4; ++kt) {
            ushort h[4], l[4];
#pragma unroll
            for (int r = 0; r < 4; ++r) {
                const float p = s[kt][r];
                h[r] = f2bf(p);
                l[r] = f2bf(p - bf2f(h[r]));
            }
            uint2 ph; ph.x = pk2(h[0],h[1]); ph.y = pk2(h[2],h[3]);
            uint2 pl; pl.x = pk2(l[0],l[1]); pl.y = pk2(l[2],l[3]);
            *(uint2*)&p_bf[w][0][ql][kt*16 + g*4] = ph;
            *(uint2*)&p_bf[w][1][ql][kt*16 + g*4] = pl;
        }
        __asm__ volatile("s_waitcnt lgkmcnt(0)" ::: "memory");
        __builtin_amdgcn_sched_barrier(0);

#pragma unroll
        for (int sj = 0; sj < 2; ++sj) {
            const short8 ph = *(const short8*)&p_bf[w][0][ql][sj*32 + g*8];
            const short8 pl = *(const short8*)&p_bf[w][1][ql][sj*32 + g*8];
#pragma unroll
            for (int dt = 0; dt < 4; ++dt) {
                const short8 vh = *(const short8*)&V_lds[0][dt*16 + ql][sj*32 + g*8];
                const short8 vl = *(const short8*)&V_lds[1][dt*16 + ql][sj*32 + g*8];
                acc[dt] = __builtin_amdgcn_mfma_f32_16x16x32_bf16(ph, vh, acc[dt], 0, 0, 0);
                acc[dt] = __builtin_amdgcn_mfma_f32_16x16x32_bf16(ph, vl, acc[dt], 0, 0, 0);
                acc[dt] = __builtin_amdgcn_mfma_f32_16x16x32_bf16(pl, vh, acc[dt], 0, 0, 0);
            }
        }
    }

    float invl[4];
#pragma unroll
    for (int r = 0; r < 4; ++r) invl[r] = 1.0f / __shfl(l_run, g*4 + r);
    float* ob = O + ((size_t)(bh >> 4) * T_SEQ + qr0) * D_MODEL + (bh & 15) * HD;
#pragma unroll
    for (int dt = 0; dt < 4; ++dt)
#pragma unroll
        for (int r = 0; r < 4; ++r)
            ob[(size_t)(g*4 + r) * D_MODEL + dt*16 + ql] = acc[dt][r] * invl[r];
}

// ---------------------------------------------------------------------------
extern "C" void kernel_launch(void* const* d_in, const int* in_sizes, int n_in,
                              void* d_out, int out_size, void* d_ws, size_t ws_size,
                              hipStream_t stream)
{
    const float* x  = (const float*)d_in[0];
    const float* Wq = (const float*)d_in[1];
    const float* Wk = (const float*)d_in[2];
    const float* Wv = (const float*)d_in[3];
    const float* Wo = (const float*)d_in[4];
    const float* bo = (const float*)d_in[5];
    float* out = (float*)d_out;

    const size_t SZ = (size_t)B_SZ * NH * T_SEQ * HD;   // 8,388,608
    float*  ws  = (float*)d_ws;
    float*  Qb  = ws;                   // fp32 [B,H,T,hd]     (32 MB)
    float*  Oa  = ws + SZ;              // fp32 [B,T,D]        (32 MB)
    ushort* Khi = (ushort*)(ws + 2*SZ); // bf16 [B,H,T,hd]x4   (64 MB)
    ushort* Klo = Khi + SZ;
    ushort* Vhi = Klo + SZ;
    ushort* Vlo = Vhi + SZ;

    // W-split scratch: Wq/Wk/Wv splits live in Oa (dead until attn);
    // Wo split lives in Qb (dead after attn). 2 MB each.
    ushort* WhA = (ushort*)Oa;          // 1M ushorts
    ushort* WlA = WhA + (size_t)D_MODEL*D_MODEL;
    ushort* WhB = (ushort*)Qb;
    ushort* WlB = WhB + (size_t)D_MODEL*D_MODEL;

    dim3 blk(256);
    dim3 gp(D_MODEL/128, (B_SZ*T_SEQ)/128);   // (8, 64)
    const int wsg = (D_MODEL*D_MODEL) / (256*4);  // 1024 blocks

    // Q projection (fp32 scatter)
    wsplit<<<wsg, blk, 0, stream>>>(Wq, WhA, WlA);
    gemm_mfma<1><<<gp, blk, 0, stream>>>(x, WhA, WlA, nullptr, Qb, nullptr, nullptr);
    // K projection (split-bf16 scatter)
    wsplit<<<wsg, blk, 0, stream>>>(Wk, WhA, WlA);
    gemm_mfma<2><<<gp, blk, 0, stream>>>(x, WhA, WlA, nullptr, nullptr, Khi, Klo);
    // V projection
    wsplit<<<wsg, blk, 0, stream>>>(Wv, WhA, WlA);
    gemm_mfma<2><<<gp, blk, 0, stream>>>(x, WhA, WlA, nullptr, nullptr, Vhi, Vlo);

    // attention -> Oa (overwrites W-split scratch; safe, it's dead)
    dim3 gatt(T_SEQ/64, B_SZ*NH);       // (32, 64)
    attn_mfma<<<gatt, blk, 0, stream>>>(Qb, Khi, Klo, Vhi, Vlo, Oa);

    // output projection (+bias); Wo split into Qb region (dead after attn)
    wsplit<<<wsg, blk, 0, stream>>>(Wo, WhB, WlB);
    gemm_mfma<0><<<gp, blk, 0, stream>>>(Oa, WhB, WlB, bo, out, nullptr, nullptr);
}